// Round 5
// baseline (157.159 us; speedup 1.0000x reference)
//
#include <hip/hip_runtime.h>
#include <cstdint>
#include <cstddef>

#define B_   32
#define N_   256
#define C_   256
#define DFF_ 1024

typedef unsigned short ushort_t;
typedef __attribute__((ext_vector_type(8))) short bf16x8;
typedef __attribute__((ext_vector_type(4))) float f32x4;

__device__ __forceinline__ ushort_t f2bf(float f) {
    unsigned u = __builtin_bit_cast(unsigned, f);
    u += 0x7FFFu + ((u >> 16) & 1u);
    return (ushort_t)(u >> 16);
}

// 128B-row swizzle: XOR byte-bits 4-6 with row bits 7-9 -> involution
__device__ __forceinline__ unsigned swz64(unsigned a) {
    return a ^ (((a >> 7) & 7u) << 4);
}

#define GLL(src, dst) __builtin_amdgcn_global_load_lds( \
    (const __attribute__((address_space(1))) void*)(src), \
    (__attribute__((address_space(3))) void*)(dst), 16, 0, 0)

// ======== prep: blocks 0-31 geo, block 32 bnprep, blocks 33-672 wprep ========
__global__ void k_prep(const float* __restrict__ coords,
                       ushort_t* __restrict__ nbr, int* __restrict__ ncnt,
                       const float* g0, const float* b0, const float* m0, const float* v0,
                       const float* g1, const float* b1, const float* m1, const float* v1,
                       const float* g2, const float* b2, const float* m2, const float* v2,
                       float* __restrict__ sh, float* __restrict__ coords_out,
                       const float* __restrict__ pw, const float* __restrict__ gi,
                       const float* __restrict__ ff1, const float* __restrict__ ff2,
                       ushort_t* __restrict__ tpw, ushort_t* __restrict__ tgi,
                       ushort_t* __restrict__ tff1, ushort_t* __restrict__ tff2) {
    int bid = blockIdx.x;
    if (bid < B_) {
        // ---- geo ----
        int b = bid, n = threadIdx.x;
        __shared__ float se[N_], sp[N_];
        __shared__ int sge[N_], sgp[N_];
        float eta = coords[(b * N_ + n) * 2 + 0];
        float phi = coords[(b * N_ + n) * 2 + 1];
        coords_out[b * 512 + n] = coords[b * 512 + n];
        coords_out[b * 512 + 256 + n] = coords[b * 512 + 256 + n];
        se[n] = eta; sp[n] = phi;
        __syncthreads();
        for (int s = 128; s > 0; s >>= 1) {
            if (n < s) {
                se[n] = fminf(se[n], se[n + s]);
                sp[n] = fminf(sp[n], sp[n + s]);
            }
            __syncthreads();
        }
        float emin = se[0], pmin = sp[0];
        int gi2 = (int)((eta - emin) / 0.1f); gi2 = gi2 < 0 ? 0 : (gi2 > 127 ? 127 : gi2);
        int pi = (int)((phi - pmin) / 0.1f); pi = pi < 0 ? 0 : (pi > 127 ? 127 : pi);
        sge[n] = gi2; sgp[n] = pi;
        __syncthreads();
        int cnt = 0;
        ushort_t* out = nbr + ((size_t)b * N_ + n) * N_;
        for (int m = 0; m < N_; ++m) {
            int dh = sge[m] - gi2 + 3;
            int dv = sgp[m] - pi + 3;
            if (((unsigned)dh < 8u) && ((unsigned)dv < 8u))
                out[cnt++] = (ushort_t)(m | ((dh * 8 + dv) << 8));
        }
        ncnt[b * N_ + n] = cnt;
    } else if (bid == B_) {
        // ---- bnprep ----
        int c = threadIdx.x;
        float s;
        s = g0[c] * rsqrtf(v0[c] + 1e-3f); sh[c]        = s; sh[256 + c]  = b0[c] - m0[c] * s;
        s = g1[c] * rsqrtf(v1[c] + 1e-3f); sh[512 + c]  = s; sh[768 + c]  = b1[c] - m1[c] * s;
        s = g2[c] * rsqrtf(v2[c] + 1e-3f); sh[1024 + c] = s; sh[1280 + c] = b2[c] - m2[c] * s;
    } else {
        // ---- wprep: transpose [K][N] fp32 -> [N][K] bf16 ----
        __shared__ float s[32][33];
        int t2 = bid - (B_ + 1);
        const float* W; ushort_t* T; int K, Nn, t;
        if (t2 < 64)       { W = pw;  T = tpw;  K = 256;  Nn = 256;  t = t2; }
        else if (t2 < 128) { W = gi;  T = tgi;  K = 256;  Nn = 256;  t = t2 - 64; }
        else if (t2 < 384) { W = ff1; T = tff1; K = 256;  Nn = 1024; t = t2 - 128; }
        else               { W = ff2; T = tff2; K = 1024; Nn = 256;  t = t2 - 384; }
        int ntiles_n = Nn >> 5;
        int n0 = (t % ntiles_n) << 5, k0 = (t / ntiles_n) << 5;
        int tx = threadIdx.x & 31, ty = threadIdx.x >> 5;
        #pragma unroll
        for (int j = 0; j < 4; ++j)
            s[ty + j * 8][tx] = W[(size_t)(k0 + ty + j * 8) * Nn + n0 + tx];
        __syncthreads();
        #pragma unroll
        for (int j = 0; j < 4; ++j)
            T[(size_t)(n0 + ty + j * 8) * K + k0 + tx] = f2bf(s[tx][ty + j * 8]);
    }
}

// ---- shared GEMM core: A (32x256, 16KB) and W (256x256, 128KB) LDS-resident ----
__device__ __forceinline__ void gemm_core(const ushort_t* sA, const ushort_t* sW,
                                          int lane, int wv, f32x4 acc[2][4]) {
    int l16 = lane & 15, g = (lane >> 4) & 3;
    unsigned oA[2][2], oB[4][2];
    #pragma unroll
    for (int mi = 0; mi < 2; ++mi)
        #pragma unroll
        for (int kk = 0; kk < 2; ++kk)
            oA[mi][kk] = swz64((unsigned)(((mi * 16 + l16) << 7) + (kk << 6) + (g << 4)));
    #pragma unroll
    for (int ni = 0; ni < 4; ++ni)
        #pragma unroll
        for (int kk = 0; kk < 2; ++kk)
            oB[ni][kk] = swz64((unsigned)(((wv * 64 + ni * 16 + l16) << 7) + (kk << 6) + (g << 4)));
    #pragma unroll
    for (int kp = 0; kp < 4; ++kp) {
        const char* cA = (const char*)sA + kp * 4096;
        const char* cW = (const char*)sW + kp * 32768;
        #pragma unroll
        for (int kk = 0; kk < 2; ++kk) {
            bf16x8 a0 = *(const bf16x8*)(cA + oA[0][kk]);
            bf16x8 a1 = *(const bf16x8*)(cA + oA[1][kk]);
            bf16x8 b0 = *(const bf16x8*)(cW + oB[0][kk]);
            bf16x8 b1 = *(const bf16x8*)(cW + oB[1][kk]);
            bf16x8 b2 = *(const bf16x8*)(cW + oB[2][kk]);
            bf16x8 b3 = *(const bf16x8*)(cW + oB[3][kk]);
            acc[0][0] = __builtin_amdgcn_mfma_f32_16x16x32_bf16(a0, b0, acc[0][0], 0, 0, 0);
            acc[0][1] = __builtin_amdgcn_mfma_f32_16x16x32_bf16(a0, b1, acc[0][1], 0, 0, 0);
            acc[0][2] = __builtin_amdgcn_mfma_f32_16x16x32_bf16(a0, b2, acc[0][2], 0, 0, 0);
            acc[0][3] = __builtin_amdgcn_mfma_f32_16x16x32_bf16(a0, b3, acc[0][3], 0, 0, 0);
            acc[1][0] = __builtin_amdgcn_mfma_f32_16x16x32_bf16(a1, b0, acc[1][0], 0, 0, 0);
            acc[1][1] = __builtin_amdgcn_mfma_f32_16x16x32_bf16(a1, b1, acc[1][1], 0, 0, 0);
            acc[1][2] = __builtin_amdgcn_mfma_f32_16x16x32_bf16(a1, b2, acc[1][2], 0, 0, 0);
            acc[1][3] = __builtin_amdgcn_mfma_f32_16x16x32_bf16(a1, b3, acc[1][3], 0, 0, 0);
        }
    }
}

// stage full Wt (256x256 bf16) into 128KB LDS, pre-swizzled source
__device__ __forceinline__ void stage_W(const ushort_t* Wt, char* sW, int tid) {
    int wv = tid >> 6, lane = tid & 63;
    #pragma unroll
    for (int q = 0; q < 32; ++q) {
        unsigned Pw = q * 4096u + (unsigned)wv * 1024u;
        unsigned P = Pw + ((unsigned)lane << 4);
        unsigned L = swz64(P);
        const ushort_t* src = Wt + ((L >> 7) & 255u) * 256u + (L >> 15) * 64u + ((L & 127u) >> 1);
        GLL(src, sW + Pw);
    }
}

// ========== k_g1: CPE -> A_lds, W_lds GEMM, LN epilogue ==========
// x1 = x + LN(cpe(x)@pw_w + pw_b);  outputs x1f fp32, x1b bf16 (linear)
__global__ __launch_bounds__(256, 1) void k_g1(
    const ushort_t* __restrict__ Wt, const float* __restrict__ x,
    const float* __restrict__ dwk, const float* __restrict__ dwb,
    const ushort_t* __restrict__ nbr, const int* __restrict__ ncnt,
    const float* __restrict__ bias, const float* __restrict__ ln_g,
    const float* __restrict__ ln_b,
    float* __restrict__ x1f, ushort_t* __restrict__ x1b) {
    __shared__ __align__(16) ushort_t sW[65536];   // 128 KB
    __shared__ __align__(16) ushort_t sA[8192];    // 16 KB
    __shared__ float red[4][32][2];
    int tid = threadIdx.x, lane = tid & 63, wv = tid >> 6;
    int rowBase = blockIdx.x * 32;
    int b = rowBase >> 8;

    stage_W(Wt, (char*)sW, tid);   // async DMA, overlaps CPE below

    // ---- CPE: 8 points per wave, interleaved for ILP ----
    int c0 = lane * 4;
    int pbase = wv * 8;
    float4 dwbv = *(const float4*)(dwb + c0);
    float4 acc8[8];
    int cnts[8];
    const ushort_t* lsts[8];
    int mx = 0;
    #pragma unroll
    for (int p = 0; p < 8; ++p) {
        int bn = rowBase + pbase + p;
        cnts[p] = ncnt[bn];
        lsts[p] = nbr + (size_t)bn * N_;
        acc8[p] = dwbv;
        mx = max(mx, cnts[p]);
    }
    const float* xb = x + (size_t)b * N_ * C_;
    for (int i = 0; i < mx; ++i) {
        #pragma unroll
        for (int p = 0; p < 8; ++p) {
            if (i < cnts[p]) {
                int pk = lsts[p][i];
                const float4 w = *(const float4*)(dwk + (pk >> 8) * C_ + c0);
                const float4 v = *(const float4*)(xb + (pk & 255) * C_ + c0);
                acc8[p].x = fmaf(w.x, v.x, acc8[p].x);
                acc8[p].y = fmaf(w.y, v.y, acc8[p].y);
                acc8[p].z = fmaf(w.z, v.z, acc8[p].z);
                acc8[p].w = fmaf(w.w, v.w, acc8[p].w);
            }
        }
    }
    // write bf16 A-tile (swizzled) into LDS
    int kp = c0 >> 6;
    #pragma unroll
    for (int p = 0; p < 8; ++p) {
        unsigned addr = kp * 4096u + swz64((unsigned)(((pbase + p) << 7) + ((c0 & 63) << 1)));
        ushort_t h[4] = {f2bf(acc8[p].x), f2bf(acc8[p].y), f2bf(acc8[p].z), f2bf(acc8[p].w)};
        *(uint2*)((char*)sA + addr) = *(const uint2*)h;
    }
    __syncthreads();   // drains GLL vmcnt + CPE ds_writes

    f32x4 acc[2][4] = {};
    gemm_core(sA, sW, lane, wv, acc);

    // ---- LN epilogue ----
    int l16 = lane & 15, g = (lane >> 4) & 3;
    float bv[4];
    #pragma unroll
    for (int ni = 0; ni < 4; ++ni) bv[ni] = bias[wv * 64 + ni * 16 + l16];
    #pragma unroll
    for (int mi = 0; mi < 2; ++mi)
        #pragma unroll
        for (int ni = 0; ni < 4; ++ni)
            #pragma unroll
            for (int j = 0; j < 4; ++j)
                acc[mi][ni][j] += bv[ni];

    #pragma unroll
    for (int mi = 0; mi < 2; ++mi)
        #pragma unroll
        for (int j = 0; j < 4; ++j) {
            float s = 0.f, q = 0.f;
            #pragma unroll
            for (int ni = 0; ni < 4; ++ni) {
                float vv = acc[mi][ni][j];
                s += vv; q += vv * vv;
            }
            #pragma unroll
            for (int off = 1; off < 16; off <<= 1) {
                s += __shfl_xor(s, off);
                q += __shfl_xor(q, off);
            }
            if (l16 == 0) {
                int r = mi * 16 + g * 4 + j;
                red[wv][r][0] = s;
                red[wv][r][1] = q;
            }
        }
    __syncthreads();
    #pragma unroll
    for (int mi = 0; mi < 2; ++mi)
        #pragma unroll
        for (int j = 0; j < 4; ++j) {
            int r = mi * 16 + g * 4 + j;
            float sum = red[0][r][0] + red[1][r][0] + red[2][r][0] + red[3][r][0];
            float sq  = red[0][r][1] + red[1][r][1] + red[2][r][1] + red[3][r][1];
            float mu = sum * (1.f / 256.f);
            float var = fmaxf(sq * (1.f / 256.f) - mu * mu, 0.f);
            float rs = rsqrtf(var + 1e-6f);
            int row = rowBase + r;
            #pragma unroll
            for (int ni = 0; ni < 4; ++ni) {
                int col = wv * 64 + ni * 16 + l16;
                size_t idx = (size_t)row * C_ + col;
                float o = x[idx] + (acc[mi][ni][j] - mu) * rs * ln_g[col] + ln_b[col];
                x1f[idx] = o;
                x1b[idx] = f2bf(o);
            }
        }
}

// ========== k_g2: gctx/gvec prologue, W_lds GEMM, bn0/bn1 epilogue ==========
// x2 = bn1(x1 + bn0(x1@gi_w2 + gi_b2 + gvec));  gvec = (mean_n x1)@gi_w1 + gi_b1
__global__ __launch_bounds__(256, 1) void k_g2(
    const ushort_t* __restrict__ Wt, const ushort_t* __restrict__ x1b,
    const float* __restrict__ x1f,
    const float* __restrict__ w1, const float* __restrict__ b1,
    const float* __restrict__ bias, const float* __restrict__ bnsh,
    float* __restrict__ x2f, ushort_t* __restrict__ x2b) {
    __shared__ __align__(16) ushort_t sW[65536];   // 128 KB
    __shared__ __align__(16) ushort_t sA[8192];    // 16 KB
    __shared__ float part[4][C_];
    __shared__ float sg[C_];
    __shared__ float sgv[C_];
    int tid = threadIdx.x, lane = tid & 63, wv = tid >> 6;
    int rowBase = blockIdx.x * 32;
    int b = rowBase >> 8;

    stage_W(Wt, (char*)sW, tid);
    // stage A (x1b rows rowBase..+31), pre-swizzled source
    #pragma unroll
    for (int q = 0; q < 4; ++q) {
        unsigned Pw = q * 4096u + (unsigned)wv * 1024u;
        unsigned P = Pw + ((unsigned)lane << 4);
        unsigned L = swz64(P);
        const ushort_t* src = x1b + (size_t)(rowBase + ((L >> 7) & 31u)) * 256u
                              + (L >> 12) * 64u + ((L & 127u) >> 1);
        GLL(src, (char*)sA + Pw);
    }

    // ---- gctx mean over this batch's 256 rows (coalesced) ----
    {
        const float* base = x1f + (size_t)b * N_ * C_ + wv * 64 * C_ + lane * 4;
        float4 a = {0.f, 0.f, 0.f, 0.f};
        for (int n = 0; n < 64; ++n) {
            float4 v = *(const float4*)(base + n * C_);
            a.x += v.x; a.y += v.y; a.z += v.z; a.w += v.w;
        }
        *(float4*)(&part[wv][lane * 4]) = a;
    }
    __syncthreads();
    {
        int j = tid;
        sg[j] = (part[0][j] + part[1][j] + part[2][j] + part[3][j]) * (1.f / 256.f);
    }
    __syncthreads();
    {
        int j = tid;
        float a2 = b1[j];
        #pragma unroll 8
        for (int c = 0; c < C_; ++c) a2 = fmaf(sg[c], w1[c * C_ + j], a2);
        sgv[j] = a2;
    }
    __syncthreads();   // also drains GLLs (vmcnt 0 before barrier)

    f32x4 acc[2][4] = {};
    gemm_core(sA, sW, lane, wv, acc);

    // ---- bn0/bn1 epilogue ----
    int l16 = lane & 15, g = (lane >> 4) & 3;
    const float* s0 = bnsh, *h0 = bnsh + 256, *s1 = bnsh + 512, *h1 = bnsh + 768;
    #pragma unroll
    for (int ni = 0; ni < 4; ++ni) {
        int col = wv * 64 + ni * 16 + l16;
        float bvv = bias[col];
        float gv = sgv[col];
        float s0v = s0[col], h0v = h0[col], s1v = s1[col], h1v = h1[col];
        #pragma unroll
        for (int mi = 0; mi < 2; ++mi)
            #pragma unroll
            for (int j = 0; j < 4; ++j) {
                int row = rowBase + mi * 16 + g * 4 + j;
                size_t idx = (size_t)row * C_ + col;
                float v = acc[mi][ni][j] + bvv + gv;
                v = v * s0v + h0v;
                float o = (x1f[idx] + v) * s1v + h1v;
                x2f[idx] = o;
                x2b[idx] = f2bf(o);
            }
    }
}

// ------ FF GEMM: BM=128, BN(128|64), BK=64, dbuf, counted vmcnt (R4) -----
template <int EPI, int BN>
__global__ __launch_bounds__(256) void k_gemm128(
    const ushort_t* __restrict__ A, const ushort_t* __restrict__ Wt,
    const float* __restrict__ bias, int K, int Nn,
    ushort_t* __restrict__ Cb, float* __restrict__ Cf,
    const float* __restrict__ residf,
    const float* __restrict__ p0, const float* __restrict__ p1) {
    const int NI = BN / 32;
    const int QB = BN / 32;
    __shared__ __align__(16) ushort_t sA[2][8192];
    __shared__ __align__(16) ushort_t sB[2][BN * 64];
    int tid = threadIdx.x;
    int lane = tid & 63, wv = tid >> 6;
    int rowBase = blockIdx.y * 128, colBase = blockIdx.x * BN;
    int l16 = lane & 15, g = (lane >> 4) & 3;
    int wr = (wv >> 1) * 64, wc = (wv & 1) * (BN / 2);

    const ushort_t* aSrc[4];
    #pragma unroll
    for (int q = 0; q < 4; ++q) {
        unsigned P = q * 4096u + (unsigned)tid * 16;
        unsigned L = swz64(P);
        aSrc[q] = A + (size_t)(rowBase + (L >> 7)) * K + ((L >> 1) & 63u);
    }
    const ushort_t* bSrc[QB];
    #pragma unroll
    for (int q = 0; q < QB; ++q) {
        unsigned P = q * 4096u + (unsigned)tid * 16;
        unsigned L = swz64(P);
        bSrc[q] = Wt + (size_t)(colBase + (L >> 7)) * K + ((L >> 1) & 63u);
    }
    unsigned wb = (unsigned)(tid >> 6) * 1024;

    unsigned oA[4][2], oB[NI][2];
    #pragma unroll
    for (int mi = 0; mi < 4; ++mi)
        #pragma unroll
        for (int kk = 0; kk < 2; ++kk)
            oA[mi][kk] = swz64((unsigned)(((wr + mi * 16 + l16) << 7) + (kk << 6) + (g << 4)));
    #pragma unroll
    for (int ni = 0; ni < NI; ++ni)
        #pragma unroll
        for (int kk = 0; kk < 2; ++kk)
            oB[ni][kk] = swz64((unsigned)(((wc + ni * 16 + l16) << 7) + (kk << 6) + (g << 4)));

    f32x4 acc[4][NI] = {};
    int nt = K >> 6;

    #pragma unroll
    for (int q = 0; q < 4; ++q) GLL(aSrc[q], (char*)sA[0] + q * 4096 + wb);
    #pragma unroll
    for (int q = 0; q < QB; ++q) GLL(bSrc[q], (char*)sB[0] + q * 4096 + wb);

    int cur = 0;
    for (int t = 0; t < nt; ++t) {
        if (t + 1 < nt) {
            int o = (t + 1) << 6;
            #pragma unroll
            for (int q = 0; q < 4; ++q) GLL(aSrc[q] + o, (char*)sA[cur ^ 1] + q * 4096 + wb);
            #pragma unroll
            for (int q = 0; q < QB; ++q) GLL(bSrc[q] + o, (char*)sB[cur ^ 1] + q * 4096 + wb);
            if constexpr (BN == 128) asm volatile("s_waitcnt vmcnt(8)" ::: "memory");
            else                     asm volatile("s_waitcnt vmcnt(6)" ::: "memory");
        } else {
            asm volatile("s_waitcnt vmcnt(0)" ::: "memory");
        }
        asm volatile("s_barrier" ::: "memory");
        const char* cA = (const char*)sA[cur];
        const char* cB = (const char*)sB[cur];
        #pragma unroll
        for (int kk = 0; kk < 2; ++kk) {
            bf16x8 af[4], bff[NI];
            #pragma unroll
            for (int mi = 0; mi < 4; ++mi) af[mi] = *(const bf16x8*)(cA + oA[mi][kk]);
            #pragma unroll
            for (int ni = 0; ni < NI; ++ni) bff[ni] = *(const bf16x8*)(cB + oB[ni][kk]);
            #pragma unroll
            for (int mi = 0; mi < 4; ++mi)
                #pragma unroll
                for (int ni = 0; ni < NI; ++ni)
                    acc[mi][ni] = __builtin_amdgcn_mfma_f32_16x16x32_bf16(af[mi], bff[ni], acc[mi][ni], 0, 0, 0);
        }
        asm volatile("s_barrier" ::: "memory");
        cur ^= 1;
    }

    #pragma unroll
    for (int ni = 0; ni < NI; ++ni) {
        int col = colBase + wc + ni * 16 + l16;
        float bvv = bias[col];
        float s0v = 0.f, h0v = 0.f;
        if constexpr (EPI == 3) { s0v = p0[col]; h0v = p1[col]; }
        #pragma unroll
        for (int mi = 0; mi < 4; ++mi)
            #pragma unroll
            for (int j = 0; j < 4; ++j) {
                int row = rowBase + wr + mi * 16 + g * 4 + j;
                size_t idx = (size_t)row * Nn + col;
                float v = acc[mi][ni][j] + bvv;
                if constexpr (EPI == 1) {
                    Cb[idx] = f2bf(fmaxf(v, 0.f));
                } else {
                    Cf[idx] = (residf[idx] + v) * s0v + h0v;
                }
            }
    }
}

extern "C" void kernel_launch(void* const* d_in, const int* in_sizes, int n_in,
                              void* d_out, int out_size, void* d_ws, size_t ws_size,
                              hipStream_t stream) {
    const float* x      = (const float*)d_in[0];
    const float* coords = (const float*)d_in[1];
    const float* dwk    = (const float*)d_in[2];
    const float* dwb    = (const float*)d_in[3];
    const float* pw_w   = (const float*)d_in[4];
    const float* pw_b   = (const float*)d_in[5];
    const float* ln_g   = (const float*)d_in[6];
    const float* ln_b   = (const float*)d_in[7];
    const float* gi_w1  = (const float*)d_in[8];
    const float* gi_b1  = (const float*)d_in[9];
    const float* gi_w2  = (const float*)d_in[10];
    const float* gi_b2  = (const float*)d_in[11];
    const float* bn0g = (const float*)d_in[12], *bn0b = (const float*)d_in[13];
    const float* bn0m = (const float*)d_in[14], *bn0v = (const float*)d_in[15];
    const float* bn1g = (const float*)d_in[16], *bn1b = (const float*)d_in[17];
    const float* bn1m = (const float*)d_in[18], *bn1v = (const float*)d_in[19];
    const float* bn2g = (const float*)d_in[20], *bn2b = (const float*)d_in[21];
    const float* bn2m = (const float*)d_in[22], *bn2v = (const float*)d_in[23];
    const float* w_ff1 = (const float*)d_in[24];
    const float* b_ff1 = (const float*)d_in[25];
    const float* w_ff2 = (const float*)d_in[26];
    const float* b_ff2 = (const float*)d_in[27];

    char* ws = (char*)d_ws;
    int*      ncnt = (int*)(ws + 0);            // 32 KB
    float*    bnsh = (float*)(ws + 32768);      // 6 KB
    ushort_t* WtPW = (ushort_t*)(ws + 65536);   // 128 KB
    ushort_t* WtGI = (ushort_t*)(ws + 196608);  // 128 KB
    ushort_t* WtF1 = (ushort_t*)(ws + 327680);  // 512 KB
    ushort_t* WtF2 = (ushort_t*)(ws + 851968);  // 512 KB
    ushort_t* nbr  = (ushort_t*)(ws + 1376256); // 4 MB
    float*    x1f  = (float*)(ws + 5570560);    // 8 MB
    ushort_t* x1b  = (ushort_t*)(ws + 13959168);// 4 MB
    float*    x2f  = (float*)(ws + 18153472);   // 8 MB
    ushort_t* x2b  = (ushort_t*)(ws + 26542080);// 4 MB
    ushort_t* u_b  = (ushort_t*)(ws + 30736384);// 16 MB
    float*    outx = (float*)d_out;

    const int M = B_ * N_;  // 8192

    // 1) geo + bnprep + wprep + coords passthrough
    k_prep<<<B_ + 1 + 640, 256, 0, stream>>>(
        coords, nbr, ncnt,
        bn0g, bn0b, bn0m, bn0v, bn1g, bn1b, bn1m, bn1v, bn2g, bn2b, bn2m, bn2v,
        bnsh, outx + (size_t)M * C_,
        pw_w, gi_w2, w_ff1, w_ff2, WtPW, WtGI, WtF1, WtF2);

    // 2) x1 = x + LN(cpe(x)@pw_w + pw_b)
    k_g1<<<M / 32, 256, 0, stream>>>(WtPW, x, dwk, dwb, nbr, ncnt,
                                     pw_b, ln_g, ln_b, x1f, x1b);

    // 3) x2 = bn1(x1 + bn0(x1@gi_w2 + gi_b2 + gvec))
    k_g2<<<M / 32, 256, 0, stream>>>(WtGI, x1b, x1f, gi_w1, gi_b1,
                                     gi_b2, bnsh, x2f, x2b);

    // 4) u = relu(x2 @ w_ff1 + b_ff1)
    k_gemm128<1, 128><<<dim3(DFF_ / 128, M / 128), 256, 0, stream>>>(
        x2b, WtF1, b_ff1, C_, DFF_, u_b, nullptr, nullptr, nullptr, nullptr);

    // 5) out = bn2(x2 + u @ w_ff2 + b_ff2)
    k_gemm128<3, 64><<<dim3(C_ / 64, M / 128), 256, 0, stream>>>(
        u_b, WtF2, b_ff2, DFF_, C_, nullptr, outx,
        x2f, bnsh + 1024, bnsh + 1280);
}

// Round 6
// 131.320 us; speedup vs baseline: 1.1968x; 1.1968x over previous
//
#include <hip/hip_runtime.h>
#include <cstdint>
#include <cstddef>

#define B_   32
#define N_   256
#define C_   256
#define DFF_ 1024

typedef unsigned short ushort_t;
typedef __attribute__((ext_vector_type(8))) short bf16x8;
typedef __attribute__((ext_vector_type(4))) float f32x4;

__device__ __forceinline__ ushort_t f2bf(float f) {
    unsigned u = __builtin_bit_cast(unsigned, f);
    u += 0x7FFFu + ((u >> 16) & 1u);
    return (ushort_t)(u >> 16);
}

// 128B-row swizzle: XOR byte-bits 4-6 with row bits 7-9 -> involution
__device__ __forceinline__ unsigned swz64(unsigned a) {
    return a ^ (((a >> 7) & 7u) << 4);
}

#define GLL(src, dst) __builtin_amdgcn_global_load_lds( \
    (const __attribute__((address_space(1))) void*)(src), \
    (__attribute__((address_space(3))) void*)(dst), 16, 0, 0)

// ======== prep: blocks 0-31 geo, block 32 bnprep, blocks 33-672 wprep ========
__global__ void k_prep(const float* __restrict__ coords,
                       ushort_t* __restrict__ nbr, int* __restrict__ ncnt,
                       const float* g0, const float* b0, const float* m0, const float* v0,
                       const float* g1, const float* b1, const float* m1, const float* v1,
                       const float* g2, const float* b2, const float* m2, const float* v2,
                       float* __restrict__ sh, float* __restrict__ coords_out,
                       const float* __restrict__ pw, const float* __restrict__ gi,
                       const float* __restrict__ ff1, const float* __restrict__ ff2,
                       ushort_t* __restrict__ tpw, ushort_t* __restrict__ tgi,
                       ushort_t* __restrict__ tff1, ushort_t* __restrict__ tff2) {
    int bid = blockIdx.x;
    if (bid < B_) {
        int b = bid, n = threadIdx.x;
        __shared__ float se[N_], sp[N_];
        __shared__ int sge[N_], sgp[N_];
        float eta = coords[(b * N_ + n) * 2 + 0];
        float phi = coords[(b * N_ + n) * 2 + 1];
        coords_out[b * 512 + n] = coords[b * 512 + n];
        coords_out[b * 512 + 256 + n] = coords[b * 512 + 256 + n];
        se[n] = eta; sp[n] = phi;
        __syncthreads();
        for (int s = 128; s > 0; s >>= 1) {
            if (n < s) {
                se[n] = fminf(se[n], se[n + s]);
                sp[n] = fminf(sp[n], sp[n + s]);
            }
            __syncthreads();
        }
        float emin = se[0], pmin = sp[0];
        int gi2 = (int)((eta - emin) / 0.1f); gi2 = gi2 < 0 ? 0 : (gi2 > 127 ? 127 : gi2);
        int pi = (int)((phi - pmin) / 0.1f); pi = pi < 0 ? 0 : (pi > 127 ? 127 : pi);
        sge[n] = gi2; sgp[n] = pi;
        __syncthreads();
        int cnt = 0;
        ushort_t* out = nbr + ((size_t)b * N_ + n) * N_;
        for (int m = 0; m < N_; ++m) {
            int dh = sge[m] - gi2 + 3;
            int dv = sgp[m] - pi + 3;
            if (((unsigned)dh < 8u) && ((unsigned)dv < 8u))
                out[cnt++] = (ushort_t)(m | ((dh * 8 + dv) << 8));
        }
        ncnt[b * N_ + n] = cnt;
    } else if (bid == B_) {
        int c = threadIdx.x;
        float s;
        s = g0[c] * rsqrtf(v0[c] + 1e-3f); sh[c]        = s; sh[256 + c]  = b0[c] - m0[c] * s;
        s = g1[c] * rsqrtf(v1[c] + 1e-3f); sh[512 + c]  = s; sh[768 + c]  = b1[c] - m1[c] * s;
        s = g2[c] * rsqrtf(v2[c] + 1e-3f); sh[1024 + c] = s; sh[1280 + c] = b2[c] - m2[c] * s;
    } else {
        __shared__ float s[32][33];
        int t2 = bid - (B_ + 1);
        const float* W; ushort_t* T; int K, Nn, t;
        if (t2 < 64)       { W = pw;  T = tpw;  K = 256;  Nn = 256;  t = t2; }
        else if (t2 < 128) { W = gi;  T = tgi;  K = 256;  Nn = 256;  t = t2 - 64; }
        else if (t2 < 384) { W = ff1; T = tff1; K = 256;  Nn = 1024; t = t2 - 128; }
        else               { W = ff2; T = tff2; K = 1024; Nn = 256;  t = t2 - 384; }
        int ntiles_n = Nn >> 5;
        int n0 = (t % ntiles_n) << 5, k0 = (t / ntiles_n) << 5;
        int tx = threadIdx.x & 31, ty = threadIdx.x >> 5;
        #pragma unroll
        for (int j = 0; j < 4; ++j)
            s[ty + j * 8][tx] = W[(size_t)(k0 + ty + j * 8) * Nn + n0 + tx];
        __syncthreads();
        #pragma unroll
        for (int j = 0; j < 4; ++j)
            T[(size_t)(n0 + ty + j * 8) * K + k0 + tx] = f2bf(s[tx][ty + j * 8]);
    }
}

// ===== CPE channel-tiled: block = (batch, 16-ch chunk); x slice LDS-resident ====
__global__ __launch_bounds__(256) void k_cpe3(
        const float* __restrict__ x, const ushort_t* __restrict__ nbr,
        const int* __restrict__ ncnt, const float* __restrict__ dwk,
        const float* __restrict__ dwb, ushort_t* __restrict__ t0) {
    int bc = blockIdx.x;
    int b = bc >> 4, ch0 = (bc & 15) << 4;
    __shared__ float xs[256][16];   // 16 KB
    __shared__ float wk[64][16];    // 4 KB
    int tid = threadIdx.x;
    int r4 = tid >> 2, q = (tid & 3) << 2;
    const float* xb = x + (size_t)b * N_ * C_;
    #pragma unroll
    for (int pass = 0; pass < 4; ++pass) {
        int row = pass * 64 + r4;
        *(float4*)&xs[row][q] = *(const float4*)(xb + row * C_ + ch0 + q);
    }
    *(float4*)&wk[r4][q] = *(const float4*)(dwk + r4 * C_ + ch0 + q);
    int c = tid & 15, pg = tid >> 4;
    float dwbv = dwb[ch0 + c];
    __syncthreads();
    #pragma unroll 2
    for (int it = 0; it < 16; ++it) {
        int p = pg * 16 + it;
        int bn = b * N_ + p;
        int cnt = ncnt[bn];
        const ushort_t* lst = nbr + (size_t)bn * N_;
        float acc = dwbv;
        for (int i = 0; i < cnt; ++i) {
            int pk = lst[i];
            acc = fmaf(wk[pk >> 8][c], xs[pk & 255][c], acc);
        }
        t0[(size_t)bn * C_ + ch0 + c] = f2bf(acc);
    }
}

// ---- full-row GEMM: BM=32, BN=256, BK=64, 4 waves; dbuf staging ----
// EPI 4: h=acc+bias; LN over 256 cols; x1 = resid + LN*p0+p1 -> Cf,Cb; emits partial colsums
// EPI 2: prologue gctx(partial)+gvec; v=acc+bias+gvec; v=v*p0+p1; o=(resid+v)*p2+p3 -> Cf,Cb
template <int EPI>
__global__ __launch_bounds__(256) void k_gemmrow(
    const ushort_t* __restrict__ A, const ushort_t* __restrict__ Wt,
    const float* __restrict__ bias,
    ushort_t* __restrict__ Cb, float* __restrict__ Cf,
    const float* __restrict__ residf,
    const float* __restrict__ p0, const float* __restrict__ p1,
    const float* __restrict__ p2, const float* __restrict__ p3,
    float* __restrict__ partial, const float* __restrict__ w1,
    const float* __restrict__ b1) {
    const int K = 256;
    __shared__ __align__(16) ushort_t sA[2][2048];    // 32 x 64
    __shared__ __align__(16) ushort_t sB[2][16384];   // 256 x 64
    __shared__ float red[4][32][2];
    __shared__ float sg[C_];
    __shared__ float sgv[C_];
    int tid = threadIdx.x;
    int lane = tid & 63, wv = tid >> 6;
    int rowBase = blockIdx.x * 32;
    int l16 = lane & 15, g = (lane >> 4) & 3;

    unsigned PA = (unsigned)tid * 16;
    unsigned LA = swz64(PA);
    const ushort_t* aSrc = A + (size_t)(rowBase + (LA >> 7)) * K + ((LA >> 1) & 63u);
    const ushort_t* bSrc[8];
    #pragma unroll
    for (int q = 0; q < 8; ++q) {
        unsigned P = q * 4096u + (unsigned)tid * 16;
        unsigned L = swz64(P);
        bSrc[q] = Wt + (size_t)(L >> 7) * K + ((L >> 1) & 63u);
    }
    unsigned wb = (unsigned)(tid >> 6) * 1024;

    unsigned oA[2][2], oB[4][2];
    #pragma unroll
    for (int mi = 0; mi < 2; ++mi)
        #pragma unroll
        for (int kk = 0; kk < 2; ++kk)
            oA[mi][kk] = swz64((unsigned)(((mi * 16 + l16) << 7) + (kk << 6) + (g << 4)));
    #pragma unroll
    for (int ni = 0; ni < 4; ++ni)
        #pragma unroll
        for (int kk = 0; kk < 2; ++kk)
            oB[ni][kk] = swz64((unsigned)(((wv * 64 + ni * 16 + l16) << 7) + (kk << 6) + (g << 4)));

    f32x4 acc[2][4] = {};
    const int nt = K >> 6;  // 4

    // prologue: stage tile 0 into buf 0 (async)
    GLL(aSrc, (char*)sA[0] + wb);
    #pragma unroll
    for (int q = 0; q < 8; ++q) GLL(bSrc[q], (char*)sB[0] + q * 4096 + wb);

    if constexpr (EPI == 2) {
        // gctx from per-block partial colsums, then gvec (overlaps DMA)
        int j = tid;
        int pb = (blockIdx.x >> 3) << 3;
        float s = 0.f;
        #pragma unroll
        for (int k = 0; k < 8; ++k) s += partial[(size_t)(pb + k) * C_ + j];
        sg[j] = s * (1.f / 256.f);
        __syncthreads();
        float a2 = b1[j];
        #pragma unroll 8
        for (int c2 = 0; c2 < C_; ++c2) a2 = fmaf(sg[c2], w1[c2 * C_ + j], a2);
        sgv[j] = a2;
        __syncthreads();
    }

    int cur = 0;
    for (int t = 0; t < nt; ++t) {
        if (t + 1 < nt) {
            int o = (t + 1) << 6;
            GLL(aSrc + o, (char*)sA[cur ^ 1] + wb);
            #pragma unroll
            for (int q = 0; q < 8; ++q) GLL(bSrc[q] + o, (char*)sB[cur ^ 1] + q * 4096 + wb);
            asm volatile("s_waitcnt vmcnt(9)" ::: "memory");
        } else {
            asm volatile("s_waitcnt vmcnt(0)" ::: "memory");
        }
        asm volatile("s_barrier" ::: "memory");
        const char* cA = (const char*)sA[cur];
        const char* cB = (const char*)sB[cur];
        #pragma unroll
        for (int kk = 0; kk < 2; ++kk) {
            bf16x8 a0 = *(const bf16x8*)(cA + oA[0][kk]);
            bf16x8 a1 = *(const bf16x8*)(cA + oA[1][kk]);
            bf16x8 b0 = *(const bf16x8*)(cB + oB[0][kk]);
            bf16x8 b1v = *(const bf16x8*)(cB + oB[1][kk]);
            bf16x8 b2 = *(const bf16x8*)(cB + oB[2][kk]);
            bf16x8 b3 = *(const bf16x8*)(cB + oB[3][kk]);
            acc[0][0] = __builtin_amdgcn_mfma_f32_16x16x32_bf16(a0, b0, acc[0][0], 0, 0, 0);
            acc[0][1] = __builtin_amdgcn_mfma_f32_16x16x32_bf16(a0, b1v, acc[0][1], 0, 0, 0);
            acc[0][2] = __builtin_amdgcn_mfma_f32_16x16x32_bf16(a0, b2, acc[0][2], 0, 0, 0);
            acc[0][3] = __builtin_amdgcn_mfma_f32_16x16x32_bf16(a0, b3, acc[0][3], 0, 0, 0);
            acc[1][0] = __builtin_amdgcn_mfma_f32_16x16x32_bf16(a1, b0, acc[1][0], 0, 0, 0);
            acc[1][1] = __builtin_amdgcn_mfma_f32_16x16x32_bf16(a1, b1v, acc[1][1], 0, 0, 0);
            acc[1][2] = __builtin_amdgcn_mfma_f32_16x16x32_bf16(a1, b2, acc[1][2], 0, 0, 0);
            acc[1][3] = __builtin_amdgcn_mfma_f32_16x16x32_bf16(a1, b3, acc[1][3], 0, 0, 0);
        }
        asm volatile("s_barrier" ::: "memory");
        cur ^= 1;
    }

    // add bias
    float bv[4];
    #pragma unroll
    for (int ni = 0; ni < 4; ++ni) bv[ni] = bias[wv * 64 + ni * 16 + l16];
    #pragma unroll
    for (int mi = 0; mi < 2; ++mi)
        #pragma unroll
        for (int ni = 0; ni < 4; ++ni)
            #pragma unroll
            for (int j = 0; j < 4; ++j)
                acc[mi][ni][j] += bv[ni];

    if constexpr (EPI == 4) {
        #pragma unroll
        for (int mi = 0; mi < 2; ++mi)
            #pragma unroll
            for (int j = 0; j < 4; ++j) {
                float s = 0.f, q = 0.f;
                #pragma unroll
                for (int ni = 0; ni < 4; ++ni) {
                    float vv = acc[mi][ni][j];
                    s += vv; q += vv * vv;
                }
                #pragma unroll
                for (int off = 1; off < 16; off <<= 1) {
                    s += __shfl_xor(s, off);
                    q += __shfl_xor(q, off);
                }
                if (l16 == 0) {
                    int r = mi * 16 + g * 4 + j;
                    red[wv][r][0] = s;
                    red[wv][r][1] = q;
                }
            }
        __syncthreads();
        float colsum[4] = {0.f, 0.f, 0.f, 0.f};
        #pragma unroll
        for (int mi = 0; mi < 2; ++mi)
            #pragma unroll
            for (int j = 0; j < 4; ++j) {
                int r = mi * 16 + g * 4 + j;
                float sum = red[0][r][0] + red[1][r][0] + red[2][r][0] + red[3][r][0];
                float sq  = red[0][r][1] + red[1][r][1] + red[2][r][1] + red[3][r][1];
                float mu = sum * (1.f / 256.f);
                float var = fmaxf(sq * (1.f / 256.f) - mu * mu, 0.f);
                float rs = rsqrtf(var + 1e-6f);
                int row = rowBase + r;
                #pragma unroll
                for (int ni = 0; ni < 4; ++ni) {
                    int col = wv * 64 + ni * 16 + l16;
                    size_t idx = (size_t)row * C_ + col;
                    float o = residf[idx] + (acc[mi][ni][j] - mu) * rs * p0[col] + p1[col];
                    Cf[idx] = o;
                    Cb[idx] = f2bf(o);
                    colsum[ni] += o;
                }
            }
        // per-block column sums of x1 (for gctx) — reduce over the 4 row-groups
        #pragma unroll
        for (int ni = 0; ni < 4; ++ni) {
            float s = colsum[ni];
            s += __shfl_xor(s, 16);
            s += __shfl_xor(s, 32);
            if (g == 0) partial[(size_t)blockIdx.x * C_ + wv * 64 + ni * 16 + l16] = s;
        }
    } else {  // EPI == 2
        #pragma unroll
        for (int ni = 0; ni < 4; ++ni) {
            int col = wv * 64 + ni * 16 + l16;
            float gv = sgv[col];
            float s0v = p0[col], h0v = p1[col], s1v = p2[col], h1v = p3[col];
            #pragma unroll
            for (int mi = 0; mi < 2; ++mi)
                #pragma unroll
                for (int j = 0; j < 4; ++j) {
                    int row = rowBase + mi * 16 + g * 4 + j;
                    size_t idx = (size_t)row * C_ + col;
                    float v = acc[mi][ni][j] + gv;
                    v = v * s0v + h0v;
                    float o = (residf[idx] + v) * s1v + h1v;
                    Cf[idx] = o;
                    Cb[idx] = f2bf(o);
                }
        }
    }
}

// ------ FF GEMM: BM=128, BN(128|64), BK=64, dbuf, counted vmcnt -----
template <int EPI, int BN>
__global__ __launch_bounds__(256) void k_gemm128(
    const ushort_t* __restrict__ A, const ushort_t* __restrict__ Wt,
    const float* __restrict__ bias, int K, int Nn,
    ushort_t* __restrict__ Cb, float* __restrict__ Cf,
    const float* __restrict__ residf,
    const float* __restrict__ p0, const float* __restrict__ p1) {
    const int NI = BN / 32;
    const int QB = BN / 32;
    __shared__ __align__(16) ushort_t sA[2][8192];
    __shared__ __align__(16) ushort_t sB[2][BN * 64];
    int tid = threadIdx.x;
    int lane = tid & 63, wv = tid >> 6;
    int rowBase = blockIdx.y * 128, colBase = blockIdx.x * BN;
    int l16 = lane & 15, g = (lane >> 4) & 3;
    int wr = (wv >> 1) * 64, wc = (wv & 1) * (BN / 2);

    const ushort_t* aSrc[4];
    #pragma unroll
    for (int q = 0; q < 4; ++q) {
        unsigned P = q * 4096u + (unsigned)tid * 16;
        unsigned L = swz64(P);
        aSrc[q] = A + (size_t)(rowBase + (L >> 7)) * K + ((L >> 1) & 63u);
    }
    const ushort_t* bSrc[QB];
    #pragma unroll
    for (int q = 0; q < QB; ++q) {
        unsigned P = q * 4096u + (unsigned)tid * 16;
        unsigned L = swz64(P);
        bSrc[q] = Wt + (size_t)(colBase + (L >> 7)) * K + ((L >> 1) & 63u);
    }
    unsigned wb = (unsigned)(tid >> 6) * 1024;

    unsigned oA[4][2], oB[NI][2];
    #pragma unroll
    for (int mi = 0; mi < 4; ++mi)
        #pragma unroll
        for (int kk = 0; kk < 2; ++kk)
            oA[mi][kk] = swz64((unsigned)(((wr + mi * 16 + l16) << 7) + (kk << 6) + (g << 4)));
    #pragma unroll
    for (int ni = 0; ni < NI; ++ni)
        #pragma unroll
        for (int kk = 0; kk < 2; ++kk)
            oB[ni][kk] = swz64((unsigned)(((wc + ni * 16 + l16) << 7) + (kk << 6) + (g << 4)));

    f32x4 acc[4][NI] = {};
    int nt = K >> 6;

    #pragma unroll
    for (int q = 0; q < 4; ++q) GLL(aSrc[q], (char*)sA[0] + q * 4096 + wb);
    #pragma unroll
    for (int q = 0; q < QB; ++q) GLL(bSrc[q], (char*)sB[0] + q * 4096 + wb);

    int cur = 0;
    for (int t = 0; t < nt; ++t) {
        if (t + 1 < nt) {
            int o = (t + 1) << 6;
            #pragma unroll
            for (int q = 0; q < 4; ++q) GLL(aSrc[q] + o, (char*)sA[cur ^ 1] + q * 4096 + wb);
            #pragma unroll
            for (int q = 0; q < QB; ++q) GLL(bSrc[q] + o, (char*)sB[cur ^ 1] + q * 4096 + wb);
            if constexpr (BN == 128) asm volatile("s_waitcnt vmcnt(8)" ::: "memory");
            else                     asm volatile("s_waitcnt vmcnt(6)" ::: "memory");
        } else {
            asm volatile("s_waitcnt vmcnt(0)" ::: "memory");
        }
        asm volatile("s_barrier" ::: "memory");
        const char* cA = (const char*)sA[cur];
        const char* cB = (const char*)sB[cur];
        #pragma unroll
        for (int kk = 0; kk < 2; ++kk) {
            bf16x8 af[4], bff[NI];
            #pragma unroll
            for (int mi = 0; mi < 4; ++mi) af[mi] = *(const bf16x8*)(cA + oA[mi][kk]);
            #pragma unroll
            for (int ni = 0; ni < NI; ++ni) bff[ni] = *(const bf16x8*)(cB + oB[ni][kk]);
            #pragma unroll
            for (int mi = 0; mi < 4; ++mi)
                #pragma unroll
                for (int ni = 0; ni < NI; ++ni)
                    acc[mi][ni] = __builtin_amdgcn_mfma_f32_16x16x32_bf16(af[mi], bff[ni], acc[mi][ni], 0, 0, 0);
        }
        asm volatile("s_barrier" ::: "memory");
        cur ^= 1;
    }

    #pragma unroll
    for (int ni = 0; ni < NI; ++ni) {
        int col = colBase + wc + ni * 16 + l16;
        float bvv = bias[col];
        float s0v = 0.f, h0v = 0.f;
        if constexpr (EPI == 3) { s0v = p0[col]; h0v = p1[col]; }
        #pragma unroll
        for (int mi = 0; mi < 4; ++mi)
            #pragma unroll
            for (int j = 0; j < 4; ++j) {
                int row = rowBase + wr + mi * 16 + g * 4 + j;
                size_t idx = (size_t)row * Nn + col;
                float v = acc[mi][ni][j] + bvv;
                if constexpr (EPI == 1) {
                    Cb[idx] = f2bf(fmaxf(v, 0.f));
                } else {
                    Cf[idx] = (residf[idx] + v) * s0v + h0v;
                }
            }
    }
}

extern "C" void kernel_launch(void* const* d_in, const int* in_sizes, int n_in,
                              void* d_out, int out_size, void* d_ws, size_t ws_size,
                              hipStream_t stream) {
    const float* x      = (const float*)d_in[0];
    const float* coords = (const float*)d_in[1];
    const float* dwk    = (const float*)d_in[2];
    const float* dwb    = (const float*)d_in[3];
    const float* pw_w   = (const float*)d_in[4];
    const float* pw_b   = (const float*)d_in[5];
    const float* ln_g   = (const float*)d_in[6];
    const float* ln_b   = (const float*)d_in[7];
    const float* gi_w1  = (const float*)d_in[8];
    const float* gi_b1  = (const float*)d_in[9];
    const float* gi_w2  = (const float*)d_in[10];
    const float* gi_b2  = (const float*)d_in[11];
    const float* bn0g = (const float*)d_in[12], *bn0b = (const float*)d_in[13];
    const float* bn0m = (const float*)d_in[14], *bn0v = (const float*)d_in[15];
    const float* bn1g = (const float*)d_in[16], *bn1b = (const float*)d_in[17];
    const float* bn1m = (const float*)d_in[18], *bn1v = (const float*)d_in[19];
    const float* bn2g = (const float*)d_in[20], *bn2b = (const float*)d_in[21];
    const float* bn2m = (const float*)d_in[22], *bn2v = (const float*)d_in[23];
    const float* w_ff1 = (const float*)d_in[24];
    const float* b_ff1 = (const float*)d_in[25];
    const float* w_ff2 = (const float*)d_in[26];
    const float* b_ff2 = (const float*)d_in[27];

    char* ws = (char*)d_ws;
    int*      ncnt    = (int*)(ws + 0);             // 32 KB
    float*    bnsh    = (float*)(ws + 32768);       // 6 KB
    float*    partial = (float*)(ws + 40960);       // 256 KB
    ushort_t* WtPW    = (ushort_t*)(ws + 303104);   // 128 KB
    ushort_t* WtGI    = (ushort_t*)(ws + 434176);   // 128 KB
    ushort_t* WtF1    = (ushort_t*)(ws + 565248);   // 512 KB
    ushort_t* WtF2    = (ushort_t*)(ws + 1089536);  // 512 KB
    ushort_t* nbr     = (ushort_t*)(ws + 1613824);  // 4 MB
    float*    x1f     = (float*)(ws + 5808128);     // 8 MB
    ushort_t* x1b     = (ushort_t*)(ws + 14196736); // 4 MB
    float*    x2f     = (float*)(ws + 18391040);    // 8 MB
    ushort_t* x2b     = (ushort_t*)(ws + 26779648); // 4 MB
    ushort_t* u_b     = (ushort_t*)(ws + 30973952); // 16 MB (aliases t0)
    ushort_t* t0      = u_b;                        // t0 dead before u_b written
    float*    outx    = (float*)d_out;

    const int M = B_ * N_;  // 8192

    // 1) geo + bnprep + wprep + coords passthrough
    k_prep<<<B_ + 1 + 640, 256, 0, stream>>>(
        coords, nbr, ncnt,
        bn0g, bn0b, bn0m, bn0v, bn1g, bn1b, bn1m, bn1v, bn2g, bn2b, bn2m, bn2v,
        bnsh, outx + (size_t)M * C_,
        pw_w, gi_w2, w_ff1, w_ff2, WtPW, WtGI, WtF1, WtF2);

    // 2) t0 = cpe(x)  — channel-tiled, x LDS-resident
    k_cpe3<<<B_ * 16, 256, 0, stream>>>(x, nbr, ncnt, dwk, dwb, t0);

    // 3) x1 = x + LN(t0@pw_w + pw_b); emits per-block colsums -> partial
    k_gemmrow<4><<<M / 32, 256, 0, stream>>>(
        t0, WtPW, pw_b, x1b, x1f,
        x, ln_g, ln_b, nullptr, nullptr,
        partial, nullptr, nullptr);

    // 4) x2 = bn1(x1 + bn0(x1@gi_w2 + gi_b2 + gvec)); gvec computed in prologue
    k_gemmrow<2><<<M / 32, 256, 0, stream>>>(
        x1b, WtGI, gi_b2, x2b, x2f,
        x1f, bnsh, bnsh + 256, bnsh + 512, bnsh + 768,
        partial, gi_w1, gi_b1);

    // 5) u = relu(x2 @ w_ff1 + b_ff1)
    k_gemm128<1, 128><<<dim3(DFF_ / 128, M / 128), 256, 0, stream>>>(
        x2b, WtF1, b_ff1, C_, DFF_, u_b, nullptr, nullptr, nullptr, nullptr);

    // 6) out = bn2(x2 + u @ w_ff2 + b_ff2)
    k_gemm128<3, 64><<<dim3(C_ / 64, M / 128), 256, 0, stream>>>(
        u_b, WtF2, b_ff2, DFF_, C_, nullptr, outx,
        x2f, bnsh + 1024, bnsh + 1280);
}

// Round 7
// 103.381 us; speedup vs baseline: 1.5202x; 1.2702x over previous
//
#include <hip/hip_runtime.h>
#include <cstdint>
#include <cstddef>

#define B_   32
#define N_   256
#define C_   256
#define DFF_ 1024

typedef unsigned short ushort_t;
typedef __attribute__((ext_vector_type(8))) short bf16x8;
typedef __attribute__((ext_vector_type(4))) float f32x4;

__device__ __forceinline__ ushort_t f2bf(float f) {
    unsigned u = __builtin_bit_cast(unsigned, f);
    u += 0x7FFFu + ((u >> 16) & 1u);
    return (ushort_t)(u >> 16);
}

// 128B-row swizzle: XOR byte-bits 4-6 with row bits 7-9 -> involution
__device__ __forceinline__ unsigned swz64(unsigned a) {
    return a ^ (((a >> 7) & 7u) << 4);
}

#define GLL(src, dst) __builtin_amdgcn_global_load_lds( \
    (const __attribute__((address_space(1))) void*)(src), \
    (__attribute__((address_space(3))) void*)(dst), 16, 0, 0)

// ======== prep: blocks 0-31 geo, block 32 bnprep, blocks 33-672 wprep ========
__global__ void k_prep(const float* __restrict__ coords,
                       ushort_t* __restrict__ nbr, int* __restrict__ ncnt,
                       const float* g0, const float* b0, const float* m0, const float* v0,
                       const float* g1, const float* b1, const float* m1, const float* v1,
                       const float* g2, const float* b2, const float* m2, const float* v2,
                       float* __restrict__ sh, float* __restrict__ coords_out,
                       const float* __restrict__ pw, const float* __restrict__ gi,
                       const float* __restrict__ ff1, const float* __restrict__ ff2,
                       ushort_t* __restrict__ tpw, ushort_t* __restrict__ tgi,
                       ushort_t* __restrict__ tff1, ushort_t* __restrict__ tff2) {
    int bid = blockIdx.x;
    if (bid < B_) {
        int b = bid, n = threadIdx.x;
        __shared__ float se[N_], sp[N_];
        __shared__ int sge[N_], sgp[N_];
        float eta = coords[(b * N_ + n) * 2 + 0];
        float phi = coords[(b * N_ + n) * 2 + 1];
        coords_out[b * 512 + n] = coords[b * 512 + n];
        coords_out[b * 512 + 256 + n] = coords[b * 512 + 256 + n];
        se[n] = eta; sp[n] = phi;
        __syncthreads();
        for (int s = 128; s > 0; s >>= 1) {
            if (n < s) {
                se[n] = fminf(se[n], se[n + s]);
                sp[n] = fminf(sp[n], sp[n + s]);
            }
            __syncthreads();
        }
        float emin = se[0], pmin = sp[0];
        int gi2 = (int)((eta - emin) / 0.1f); gi2 = gi2 < 0 ? 0 : (gi2 > 127 ? 127 : gi2);
        int pi = (int)((phi - pmin) / 0.1f); pi = pi < 0 ? 0 : (pi > 127 ? 127 : pi);
        sge[n] = gi2; sgp[n] = pi;
        __syncthreads();
        int cnt = 0;
        ushort_t* out = nbr + ((size_t)b * N_ + n) * N_;
        for (int m = 0; m < N_; ++m) {
            int dh = sge[m] - gi2 + 3;
            int dv = sgp[m] - pi + 3;
            if (((unsigned)dh < 8u) && ((unsigned)dv < 8u))
                out[cnt++] = (ushort_t)(m | ((dh * 8 + dv) << 8));
        }
        ncnt[b * N_ + n] = cnt;
    } else if (bid == B_) {
        int c = threadIdx.x;
        float s;
        s = g0[c] * rsqrtf(v0[c] + 1e-3f); sh[c]        = s; sh[256 + c]  = b0[c] - m0[c] * s;
        s = g1[c] * rsqrtf(v1[c] + 1e-3f); sh[512 + c]  = s; sh[768 + c]  = b1[c] - m1[c] * s;
        s = g2[c] * rsqrtf(v2[c] + 1e-3f); sh[1024 + c] = s; sh[1280 + c] = b2[c] - m2[c] * s;
    } else {
        __shared__ float s[32][33];
        int t2 = bid - (B_ + 1);
        const float* W; ushort_t* T; int K, Nn, t;
        if (t2 < 64)       { W = pw;  T = tpw;  K = 256;  Nn = 256;  t = t2; }
        else if (t2 < 128) { W = gi;  T = tgi;  K = 256;  Nn = 256;  t = t2 - 64; }
        else if (t2 < 384) { W = ff1; T = tff1; K = 256;  Nn = 1024; t = t2 - 128; }
        else               { W = ff2; T = tff2; K = 1024; Nn = 256;  t = t2 - 384; }
        int ntiles_n = Nn >> 5;
        int n0 = (t % ntiles_n) << 5, k0 = (t / ntiles_n) << 5;
        int tx = threadIdx.x & 31, ty = threadIdx.x >> 5;
        #pragma unroll
        for (int j = 0; j < 4; ++j)
            s[ty + j * 8][tx] = W[(size_t)(k0 + ty + j * 8) * Nn + n0 + tx];
        __syncthreads();
        #pragma unroll
        for (int j = 0; j < 4; ++j)
            T[(size_t)(n0 + ty + j * 8) * K + k0 + tx] = f2bf(s[tx][ty + j * 8]);
    }
}

// ==== CPE: one wave per point, float4 channels, 4-way unrolled neighbors ====
__global__ __launch_bounds__(256) void k_cpe2(
        const float* __restrict__ x,
        const ushort_t* __restrict__ nbr, const int* __restrict__ ncnt,
        const float* __restrict__ dwk, const float* __restrict__ dwb,
        ushort_t* __restrict__ t0) {
    int wv = threadIdx.x >> 6, lane = threadIdx.x & 63;
    int bn = blockIdx.x * 4 + wv;
    int b = bn >> 8;
    int c0 = lane * 4;
    int cnt = ncnt[bn];
    const ushort_t* lst = nbr + (size_t)bn * N_;
    const float* xb = x + (size_t)b * N_ * C_;
    float4 a0 = *(const float4*)(dwb + c0);
    float4 a1 = {0.f, 0.f, 0.f, 0.f};
    float4 a2 = {0.f, 0.f, 0.f, 0.f};
    float4 a3 = {0.f, 0.f, 0.f, 0.f};
    int i = 0;
    for (; i + 4 <= cnt; i += 4) {
        int pk0 = lst[i], pk1 = lst[i + 1], pk2 = lst[i + 2], pk3 = lst[i + 3];
        float4 w0 = *(const float4*)(dwk + (pk0 >> 8) * C_ + c0);
        float4 v0 = *(const float4*)(xb + (pk0 & 255) * C_ + c0);
        float4 w1 = *(const float4*)(dwk + (pk1 >> 8) * C_ + c0);
        float4 v1 = *(const float4*)(xb + (pk1 & 255) * C_ + c0);
        float4 w2 = *(const float4*)(dwk + (pk2 >> 8) * C_ + c0);
        float4 v2 = *(const float4*)(xb + (pk2 & 255) * C_ + c0);
        float4 w3 = *(const float4*)(dwk + (pk3 >> 8) * C_ + c0);
        float4 v3 = *(const float4*)(xb + (pk3 & 255) * C_ + c0);
        a0.x = fmaf(w0.x, v0.x, a0.x); a0.y = fmaf(w0.y, v0.y, a0.y);
        a0.z = fmaf(w0.z, v0.z, a0.z); a0.w = fmaf(w0.w, v0.w, a0.w);
        a1.x = fmaf(w1.x, v1.x, a1.x); a1.y = fmaf(w1.y, v1.y, a1.y);
        a1.z = fmaf(w1.z, v1.z, a1.z); a1.w = fmaf(w1.w, v1.w, a1.w);
        a2.x = fmaf(w2.x, v2.x, a2.x); a2.y = fmaf(w2.y, v2.y, a2.y);
        a2.z = fmaf(w2.z, v2.z, a2.z); a2.w = fmaf(w2.w, v2.w, a2.w);
        a3.x = fmaf(w3.x, v3.x, a3.x); a3.y = fmaf(w3.y, v3.y, a3.y);
        a3.z = fmaf(w3.z, v3.z, a3.z); a3.w = fmaf(w3.w, v3.w, a3.w);
    }
    for (; i < cnt; ++i) {
        int pk = lst[i];
        float4 w = *(const float4*)(dwk + (pk >> 8) * C_ + c0);
        float4 v = *(const float4*)(xb + (pk & 255) * C_ + c0);
        a0.x = fmaf(w.x, v.x, a0.x); a0.y = fmaf(w.y, v.y, a0.y);
        a0.z = fmaf(w.z, v.z, a0.z); a0.w = fmaf(w.w, v.w, a0.w);
    }
    a0.x += a1.x + a2.x + a3.x;
    a0.y += a1.y + a2.y + a3.y;
    a0.z += a1.z + a2.z + a3.z;
    a0.w += a1.w + a2.w + a3.w;
    ushort4 ob; ob.x = f2bf(a0.x); ob.y = f2bf(a0.y); ob.z = f2bf(a0.z); ob.w = f2bf(a0.w);
    *(ushort4*)(t0 + (size_t)bn * C_ + c0) = ob;
}

// ---- full-row GEMM: BM=32, BN=256, BK=64, 4 waves; dbuf staging ----
// EPI 4: h=acc+bias; LN over 256 cols; x1 = resid + LN*p0+p1 -> Cf,Cb; emits partial colsums
// EPI 2: prologue gctx(partial)+gvec; v=acc+bias+gvec; v=v*p0+p1; o=(resid+v)*p2+p3 -> Cf,Cb
template <int EPI>
__global__ __launch_bounds__(256) void k_gemmrow(
    const ushort_t* __restrict__ A, const ushort_t* __restrict__ Wt,
    const float* __restrict__ bias,
    ushort_t* __restrict__ Cb, float* __restrict__ Cf,
    const float* __restrict__ residf,
    const float* __restrict__ p0, const float* __restrict__ p1,
    const float* __restrict__ p2, const float* __restrict__ p3,
    float* __restrict__ partial, const float* __restrict__ w1,
    const float* __restrict__ b1) {
    const int K = 256;
    __shared__ __align__(16) ushort_t sA[2][2048];    // 32 x 64
    __shared__ __align__(16) ushort_t sB[2][16384];   // 256 x 64
    __shared__ float red[4][32][2];
    __shared__ float sg[C_];
    __shared__ float sgv[C_];
    int tid = threadIdx.x;
    int lane = tid & 63, wv = tid >> 6;
    int rowBase = blockIdx.x * 32;
    int l16 = lane & 15, g = (lane >> 4) & 3;

    unsigned PA = (unsigned)tid * 16;
    unsigned LA = swz64(PA);
    const ushort_t* aSrc = A + (size_t)(rowBase + (LA >> 7)) * K + ((LA >> 1) & 63u);
    const ushort_t* bSrc[8];
    #pragma unroll
    for (int q = 0; q < 8; ++q) {
        unsigned P = q * 4096u + (unsigned)tid * 16;
        unsigned L = swz64(P);
        bSrc[q] = Wt + (size_t)(L >> 7) * K + ((L >> 1) & 63u);
    }
    unsigned wb = (unsigned)(tid >> 6) * 1024;

    unsigned oA[2][2], oB[4][2];
    #pragma unroll
    for (int mi = 0; mi < 2; ++mi)
        #pragma unroll
        for (int kk = 0; kk < 2; ++kk)
            oA[mi][kk] = swz64((unsigned)(((mi * 16 + l16) << 7) + (kk << 6) + (g << 4)));
    #pragma unroll
    for (int ni = 0; ni < 4; ++ni)
        #pragma unroll
        for (int kk = 0; kk < 2; ++kk)
            oB[ni][kk] = swz64((unsigned)(((wv * 64 + ni * 16 + l16) << 7) + (kk << 6) + (g << 4)));

    f32x4 acc[2][4] = {};
    const int nt = K >> 6;  // 4

    // prologue: stage tile 0 into buf 0 (async)
    GLL(aSrc, (char*)sA[0] + wb);
    #pragma unroll
    for (int q = 0; q < 8; ++q) GLL(bSrc[q], (char*)sB[0] + q * 4096 + wb);

    if constexpr (EPI == 2) {
        // gctx from per-block partial colsums, then gvec (overlaps DMA)
        int j = tid;
        int pb = (blockIdx.x >> 3) << 3;
        float s = 0.f;
        #pragma unroll
        for (int k = 0; k < 8; ++k) s += partial[(size_t)(pb + k) * C_ + j];
        sg[j] = s * (1.f / 256.f);
        __syncthreads();
        float a2 = b1[j];
        #pragma unroll 8
        for (int c2 = 0; c2 < C_; ++c2) a2 = fmaf(sg[c2], w1[c2 * C_ + j], a2);
        sgv[j] = a2;
        __syncthreads();
    }

    int cur = 0;
    for (int t = 0; t < nt; ++t) {
        if (t + 1 < nt) {
            int o = (t + 1) << 6;
            GLL(aSrc + o, (char*)sA[cur ^ 1] + wb);
            #pragma unroll
            for (int q = 0; q < 8; ++q) GLL(bSrc[q] + o, (char*)sB[cur ^ 1] + q * 4096 + wb);
            asm volatile("s_waitcnt vmcnt(9)" ::: "memory");
        } else {
            asm volatile("s_waitcnt vmcnt(0)" ::: "memory");
        }
        asm volatile("s_barrier" ::: "memory");
        const char* cA = (const char*)sA[cur];
        const char* cB = (const char*)sB[cur];
        #pragma unroll
        for (int kk = 0; kk < 2; ++kk) {
            bf16x8 a0 = *(const bf16x8*)(cA + oA[0][kk]);
            bf16x8 a1 = *(const bf16x8*)(cA + oA[1][kk]);
            bf16x8 b0 = *(const bf16x8*)(cB + oB[0][kk]);
            bf16x8 b1v = *(const bf16x8*)(cB + oB[1][kk]);
            bf16x8 b2 = *(const bf16x8*)(cB + oB[2][kk]);
            bf16x8 b3 = *(const bf16x8*)(cB + oB[3][kk]);
            acc[0][0] = __builtin_amdgcn_mfma_f32_16x16x32_bf16(a0, b0, acc[0][0], 0, 0, 0);
            acc[0][1] = __builtin_amdgcn_mfma_f32_16x16x32_bf16(a0, b1v, acc[0][1], 0, 0, 0);
            acc[0][2] = __builtin_amdgcn_mfma_f32_16x16x32_bf16(a0, b2, acc[0][2], 0, 0, 0);
            acc[0][3] = __builtin_amdgcn_mfma_f32_16x16x32_bf16(a0, b3, acc[0][3], 0, 0, 0);
            acc[1][0] = __builtin_amdgcn_mfma_f32_16x16x32_bf16(a1, b0, acc[1][0], 0, 0, 0);
            acc[1][1] = __builtin_amdgcn_mfma_f32_16x16x32_bf16(a1, b1v, acc[1][1], 0, 0, 0);
            acc[1][2] = __builtin_amdgcn_mfma_f32_16x16x32_bf16(a1, b2, acc[1][2], 0, 0, 0);
            acc[1][3] = __builtin_amdgcn_mfma_f32_16x16x32_bf16(a1, b3, acc[1][3], 0, 0, 0);
        }
        asm volatile("s_barrier" ::: "memory");
        cur ^= 1;
    }

    // add bias
    float bv[4];
    #pragma unroll
    for (int ni = 0; ni < 4; ++ni) bv[ni] = bias[wv * 64 + ni * 16 + l16];
    #pragma unroll
    for (int mi = 0; mi < 2; ++mi)
        #pragma unroll
        for (int ni = 0; ni < 4; ++ni)
            #pragma unroll
            for (int j = 0; j < 4; ++j)
                acc[mi][ni][j] += bv[ni];

    if constexpr (EPI == 4) {
        #pragma unroll
        for (int mi = 0; mi < 2; ++mi)
            #pragma unroll
            for (int j = 0; j < 4; ++j) {
                float s = 0.f, q = 0.f;
                #pragma unroll
                for (int ni = 0; ni < 4; ++ni) {
                    float vv = acc[mi][ni][j];
                    s += vv; q += vv * vv;
                }
                #pragma unroll
                for (int off = 1; off < 16; off <<= 1) {
                    s += __shfl_xor(s, off);
                    q += __shfl_xor(q, off);
                }
                if (l16 == 0) {
                    int r = mi * 16 + g * 4 + j;
                    red[wv][r][0] = s;
                    red[wv][r][1] = q;
                }
            }
        __syncthreads();
        float colsum[4] = {0.f, 0.f, 0.f, 0.f};
        #pragma unroll
        for (int mi = 0; mi < 2; ++mi)
            #pragma unroll
            for (int j = 0; j < 4; ++j) {
                int r = mi * 16 + g * 4 + j;
                float sum = red[0][r][0] + red[1][r][0] + red[2][r][0] + red[3][r][0];
                float sq  = red[0][r][1] + red[1][r][1] + red[2][r][1] + red[3][r][1];
                float mu = sum * (1.f / 256.f);
                float var = fmaxf(sq * (1.f / 256.f) - mu * mu, 0.f);
                float rs = rsqrtf(var + 1e-6f);
                int row = rowBase + r;
                #pragma unroll
                for (int ni = 0; ni < 4; ++ni) {
                    int col = wv * 64 + ni * 16 + l16;
                    size_t idx = (size_t)row * C_ + col;
                    float o = residf[idx] + (acc[mi][ni][j] - mu) * rs * p0[col] + p1[col];
                    Cf[idx] = o;
                    Cb[idx] = f2bf(o);
                    colsum[ni] += o;
                }
            }
        // per-block column sums of x1 (for gctx) — reduce over the 4 row-groups
        #pragma unroll
        for (int ni = 0; ni < 4; ++ni) {
            float s = colsum[ni];
            s += __shfl_xor(s, 16);
            s += __shfl_xor(s, 32);
            if (g == 0) partial[(size_t)blockIdx.x * C_ + wv * 64 + ni * 16 + l16] = s;
        }
    } else {  // EPI == 2
        #pragma unroll
        for (int ni = 0; ni < 4; ++ni) {
            int col = wv * 64 + ni * 16 + l16;
            float gv = sgv[col];
            float s0v = p0[col], h0v = p1[col], s1v = p2[col], h1v = p3[col];
            #pragma unroll
            for (int mi = 0; mi < 2; ++mi)
                #pragma unroll
                for (int j = 0; j < 4; ++j) {
                    int row = rowBase + mi * 16 + g * 4 + j;
                    size_t idx = (size_t)row * C_ + col;
                    float v = acc[mi][ni][j] + gv;
                    v = v * s0v + h0v;
                    float o = (residf[idx] + v) * s1v + h1v;
                    Cf[idx] = o;
                    Cb[idx] = f2bf(o);
                }
        }
    }
}

// ------ FF GEMM: BM=128, BN(128|64), BK=64, dbuf, counted vmcnt -----
template <int EPI, int BN>
__global__ __launch_bounds__(256) void k_gemm128(
    const ushort_t* __restrict__ A, const ushort_t* __restrict__ Wt,
    const float* __restrict__ bias, int K, int Nn,
    ushort_t* __restrict__ Cb, float* __restrict__ Cf,
    const float* __restrict__ residf,
    const float* __restrict__ p0, const float* __restrict__ p1) {
    const int NI = BN / 32;
    const int QB = BN / 32;
    __shared__ __align__(16) ushort_t sA[2][8192];
    __shared__ __align__(16) ushort_t sB[2][BN * 64];
    int tid = threadIdx.x;
    int lane = tid & 63, wv = tid >> 6;
    int rowBase = blockIdx.y * 128, colBase = blockIdx.x * BN;
    int l16 = lane & 15, g = (lane >> 4) & 3;
    int wr = (wv >> 1) * 64, wc = (wv & 1) * (BN / 2);

    const ushort_t* aSrc[4];
    #pragma unroll
    for (int q = 0; q < 4; ++q) {
        unsigned P = q * 4096u + (unsigned)tid * 16;
        unsigned L = swz64(P);
        aSrc[q] = A + (size_t)(rowBase + (L >> 7)) * K + ((L >> 1) & 63u);
    }
    const ushort_t* bSrc[QB];
    #pragma unroll
    for (int q = 0; q < QB; ++q) {
        unsigned P = q * 4096u + (unsigned)tid * 16;
        unsigned L = swz64(P);
        bSrc[q] = Wt + (size_t)(colBase + (L >> 7)) * K + ((L >> 1) & 63u);
    }
    unsigned wb = (unsigned)(tid >> 6) * 1024;

    unsigned oA[4][2], oB[NI][2];
    #pragma unroll
    for (int mi = 0; mi < 4; ++mi)
        #pragma unroll
        for (int kk = 0; kk < 2; ++kk)
            oA[mi][kk] = swz64((unsigned)(((wr + mi * 16 + l16) << 7) + (kk << 6) + (g << 4)));
    #pragma unroll
    for (int ni = 0; ni < NI; ++ni)
        #pragma unroll
        for (int kk = 0; kk < 2; ++kk)
            oB[ni][kk] = swz64((unsigned)(((wc + ni * 16 + l16) << 7) + (kk << 6) + (g << 4)));

    f32x4 acc[4][NI] = {};
    int nt = K >> 6;

    #pragma unroll
    for (int q = 0; q < 4; ++q) GLL(aSrc[q], (char*)sA[0] + q * 4096 + wb);
    #pragma unroll
    for (int q = 0; q < QB; ++q) GLL(bSrc[q], (char*)sB[0] + q * 4096 + wb);

    int cur = 0;
    for (int t = 0; t < nt; ++t) {
        if (t + 1 < nt) {
            int o = (t + 1) << 6;
            #pragma unroll
            for (int q = 0; q < 4; ++q) GLL(aSrc[q] + o, (char*)sA[cur ^ 1] + q * 4096 + wb);
            #pragma unroll
            for (int q = 0; q < QB; ++q) GLL(bSrc[q] + o, (char*)sB[cur ^ 1] + q * 4096 + wb);
            if constexpr (BN == 128) asm volatile("s_waitcnt vmcnt(8)" ::: "memory");
            else                     asm volatile("s_waitcnt vmcnt(6)" ::: "memory");
        } else {
            asm volatile("s_waitcnt vmcnt(0)" ::: "memory");
        }
        asm volatile("s_barrier" ::: "memory");
        const char* cA = (const char*)sA[cur];
        const char* cB = (const char*)sB[cur];
        #pragma unroll
        for (int kk = 0; kk < 2; ++kk) {
            bf16x8 af[4], bff[NI];
            #pragma unroll
            for (int mi = 0; mi < 4; ++mi) af[mi] = *(const bf16x8*)(cA + oA[mi][kk]);
            #pragma unroll
            for (int ni = 0; ni < NI; ++ni) bff[ni] = *(const bf16x8*)(cB + oB[ni][kk]);
            #pragma unroll
            for (int mi = 0; mi < 4; ++mi)
                #pragma unroll
                for (int ni = 0; ni < NI; ++ni)
                    acc[mi][ni] = __builtin_amdgcn_mfma_f32_16x16x32_bf16(af[mi], bff[ni], acc[mi][ni], 0, 0, 0);
        }
        asm volatile("s_barrier" ::: "memory");
        cur ^= 1;
    }

    #pragma unroll
    for (int ni = 0; ni < NI; ++ni) {
        int col = colBase + wc + ni * 16 + l16;
        float bvv = bias[col];
        float s0v = 0.f, h0v = 0.f;
        if constexpr (EPI == 3) { s0v = p0[col]; h0v = p1[col]; }
        #pragma unroll
        for (int mi = 0; mi < 4; ++mi)
            #pragma unroll
            for (int j = 0; j < 4; ++j) {
                int row = rowBase + wr + mi * 16 + g * 4 + j;
                size_t idx = (size_t)row * Nn + col;
                float v = acc[mi][ni][j] + bvv;
                if constexpr (EPI == 1) {
                    Cb[idx] = f2bf(fmaxf(v, 0.f));
                } else {
                    Cf[idx] = (residf[idx] + v) * s0v + h0v;
                }
            }
    }
}

extern "C" void kernel_launch(void* const* d_in, const int* in_sizes, int n_in,
                              void* d_out, int out_size, void* d_ws, size_t ws_size,
                              hipStream_t stream) {
    const float* x      = (const float*)d_in[0];
    const float* coords = (const float*)d_in[1];
    const float* dwk    = (const float*)d_in[2];
    const float* dwb    = (const float*)d_in[3];
    const float* pw_w   = (const float*)d_in[4];
    const float* pw_b   = (const float*)d_in[5];
    const float* ln_g   = (const float*)d_in[6];
    const float* ln_b   = (const float*)d_in[7];
    const float* gi_w1  = (const float*)d_in[8];
    const float* gi_b1  = (const float*)d_in[9];
    const float* gi_w2  = (const float*)d_in[10];
    const float* gi_b2  = (const float*)d_in[11];
    const float* bn0g = (const float*)d_in[12], *bn0b = (const float*)d_in[13];
    const float* bn0m = (const float*)d_in[14], *bn0v = (const float*)d_in[15];
    const float* bn1g = (const float*)d_in[16], *bn1b = (const float*)d_in[17];
    const float* bn1m = (const float*)d_in[18], *bn1v = (const float*)d_in[19];
    const float* bn2g = (const float*)d_in[20], *bn2b = (const float*)d_in[21];
    const float* bn2m = (const float*)d_in[22], *bn2v = (const float*)d_in[23];
    const float* w_ff1 = (const float*)d_in[24];
    const float* b_ff1 = (const float*)d_in[25];
    const float* w_ff2 = (const float*)d_in[26];
    const float* b_ff2 = (const float*)d_in[27];

    char* ws = (char*)d_ws;
    int*      ncnt    = (int*)(ws + 0);             // 32 KB
    float*    bnsh    = (float*)(ws + 32768);       // 6 KB
    float*    partial = (float*)(ws + 40960);       // 256 KB
    ushort_t* WtPW    = (ushort_t*)(ws + 303104);   // 128 KB
    ushort_t* WtGI    = (ushort_t*)(ws + 434176);   // 128 KB
    ushort_t* WtF1    = (ushort_t*)(ws + 565248);   // 512 KB
    ushort_t* WtF2    = (ushort_t*)(ws + 1089536);  // 512 KB
    ushort_t* nbr     = (ushort_t*)(ws + 1613824);  // 4 MB
    float*    x1f     = (float*)(ws + 5808128);     // 8 MB
    ushort_t* x1b     = (ushort_t*)(ws + 14196736); // 4 MB
    float*    x2f     = (float*)(ws + 18391040);    // 8 MB
    ushort_t* x2b     = (ushort_t*)(ws + 26779648); // 4 MB
    ushort_t* u_b     = (ushort_t*)(ws + 30973952); // 16 MB (aliases t0)
    ushort_t* t0      = u_b;                        // t0 dead before u_b written
    float*    outx    = (float*)d_out;

    const int M = B_ * N_;  // 8192

    // 1) geo + bnprep + wprep + coords passthrough
    k_prep<<<B_ + 1 + 640, 256, 0, stream>>>(
        coords, nbr, ncnt,
        bn0g, bn0b, bn0m, bn0v, bn1g, bn1b, bn1m, bn1v, bn2g, bn2b, bn2m, bn2v,
        bnsh, outx + (size_t)M * C_,
        pw_w, gi_w2, w_ff1, w_ff2, WtPW, WtGI, WtF1, WtF2);

    // 2) t0 = cpe(x)  — wave per point, 4-way unrolled neighbor loop
    k_cpe2<<<M / 4, 256, 0, stream>>>(x, nbr, ncnt, dwk, dwb, t0);

    // 3) x1 = x + LN(t0@pw_w + pw_b); emits per-block colsums -> partial
    k_gemmrow<4><<<M / 32, 256, 0, stream>>>(
        t0, WtPW, pw_b, x1b, x1f,
        x, ln_g, ln_b, nullptr, nullptr,
        partial, nullptr, nullptr);

    // 4) x2 = bn1(x1 + bn0(x1@gi_w2 + gi_b2 + gvec)); gvec computed in prologue
    k_gemmrow<2><<<M / 32, 256, 0, stream>>>(
        x1b, WtGI, gi_b2, x2b, x2f,
        x1f, bnsh, bnsh + 256, bnsh + 512, bnsh + 768,
        partial, gi_w1, gi_b1);

    // 5) u = relu(x2 @ w_ff1 + b_ff1)
    k_gemm128<1, 128><<<dim3(DFF_ / 128, M / 128), 256, 0, stream>>>(
        x2b, WtF1, b_ff1, C_, DFF_, u_b, nullptr, nullptr, nullptr, nullptr);

    // 6) out = bn2(x2 + u @ w_ff2 + b_ff2)
    k_gemm128<3, 64><<<dim3(C_ / 64, M / 128), 256, 0, stream>>>(
        u_b, WtF2, b_ff2, DFF_, C_, nullptr, outx,
        x2f, bnsh + 1024, bnsh + 1280);
}